// Round 11
// baseline (665.439 us; speedup 1.0000x reference)
//
#include <hip/hip_runtime.h>
#include <hip/hip_bf16.h>
#include <math.h>

#define B 64
#define K 3
#define H 4096
#define V 32000
#define K1 (K + 1)

typedef short bf16x8_t __attribute__((ext_vector_type(8)));
typedef float f32x4_t __attribute__((ext_vector_type(4)));
typedef long long i64_t;

// ---------------- workspace layout (bytes) ----------------
#define OFF_TARGET  0                      // 256 int
#define OFF_TOK     1024                   // 64 int
#define OFF_THRI    2048                   // 64 uint
#define OFF_GCNT    3072                   // 1 int (global candidate count)
#define OFF_RESK    4096                   // 64 ull (8B aligned)
#define OFF_SCALE   8192                   // 128 float
#define OFF_HBUF    (1u << 20)             // B*H float (1 MB)
#define OFF_XROW    (2u << 20)             // B*H float, x row-major [b][h]
#define OFF_UF      (3u << 20)             // u 3-way bf16 split frags (3 MB)
#define OFF_XF      (6u << 20)             // x fp8 frag layout (256 KB)
#define OFF_PART    (16u << 20)            // 8 ks * H * B float = 8.4 MB; reused as candidate list by gemm2/rescore
#define OFF_LF      (48u << 20)            // lm_head fp8 frag layout (131 MB)

// out layout: accepted[256] | num_accepted[64] | next_draft[192] | next_new[256] | new_past_t[192]
#define OUT_ACC 0
#define OUT_NA  256
#define OUT_NDT 320
#define OUT_NNT 512
#define OUT_NPT 768

#define DELTA 1.5f
#define FP8SCALE 16.0f
#define INVACC (1.0f / 256.0f)
#define CAPG (2000000)     // candidate list capacity (fits in 16 MB part space)
#define CAPB 2048          // per-block LDS staging capacity

__device__ __forceinline__ unsigned short f2bf(float f) {
    unsigned int u = __float_as_uint(f);
    u += 0x7fffu + ((u >> 16) & 1u);       // round-to-nearest-even
    return (unsigned short)(u >> 16);
}
__device__ __forceinline__ float bf2f(unsigned short h) {
    return __uint_as_float(((unsigned int)h) << 16);
}
__device__ __forceinline__ uint4 mku4(const unsigned short* p) {
    return make_uint4((unsigned)p[0] | ((unsigned)p[1] << 16),
                      (unsigned)p[2] | ((unsigned)p[3] << 16),
                      (unsigned)p[4] | ((unsigned)p[5] << 16),
                      (unsigned)p[6] | ((unsigned)p[7] << 16));
}
__device__ __forceinline__ bf16x8_t mkfrag(const unsigned short* p) {
    union { uint4 q; bf16x8_t v; } u;
    u.q = mku4(p);
    return u.v;
}
// monotonic float<->uint key (larger float => larger key); all-zero init < every valid key
__device__ __forceinline__ unsigned fkey(float f) {
    unsigned u = __float_as_uint(f);
    return u ^ ((unsigned)((int)u >> 31) | 0x80000000u);
}
__device__ __forceinline__ float funkey(unsigned k) {
    unsigned u = (k & 0x80000000u) ? (k ^ 0x80000000u) : ~k;
    return __uint_as_float(u);
}
// fp32 -> OCP e4m3fn, round-to-nearest-even, saturate at 448, subnormals handled.
__device__ __forceinline__ unsigned int f2fp8(float f) {
    unsigned u = __float_as_uint(f);
    unsigned sgn = (u >> 24) & 0x80u;
    unsigned au = u & 0x7FFFFFFFu;
    if (au >= 0x43E00000u) return sgn | 0x7Eu;            // clamp to +-448
    if (au < 0x3C800000u) {                               // |f| < 2^-6: subnormal
        float a = __uint_as_float(au);
        int m = (int)rintf(a * 512.0f);                   // steps of 2^-9; m==8 -> min normal
        return sgn | (unsigned)m;
    }
    unsigned r = au + 0x7FFFFu + ((au >> 20) & 1u);       // RNE at 3 mantissa bits
    unsigned e = (r >> 23) - 120u;
    unsigned m = (r >> 20) & 7u;
    return sgn | (e << 3) | m;
}
// pack 8 floats (pre-scaled) into one fp8x8 (i64)
__device__ __forceinline__ unsigned long long pack8fp8(const float* a) {
    unsigned lo = f2fp8(a[0]) | (f2fp8(a[1]) << 8) | (f2fp8(a[2]) << 16) | (f2fp8(a[3]) << 24);
    unsigned hi = f2fp8(a[4]) | (f2fp8(a[5]) << 8) | (f2fp8(a[6]) << 16) | (f2fp8(a[7]) << 24);
    return (unsigned long long)lo | ((unsigned long long)hi << 32);
}

// ------------------------------------------------------------------
// Kernel A: row-wise argmax of logits (256 rows x 32000), first-index tie-break
__global__ void argmax_logits_kernel(const float* __restrict__ logits, int* __restrict__ target) {
    const int r = blockIdx.x;
    const float4* row = (const float4*)(logits + (size_t)r * V);
    float bv = -INFINITY;
    int bi = 0x7fffffff;
    for (int i4 = threadIdx.x; i4 < V / 4; i4 += 256) {
        float4 v = row[i4];
        int base = i4 * 4;
        if (v.x > bv) { bv = v.x; bi = base; }
        if (v.y > bv) { bv = v.y; bi = base + 1; }
        if (v.z > bv) { bv = v.z; bi = base + 2; }
        if (v.w > bv) { bv = v.w; bi = base + 3; }
    }
    __shared__ float sv[256];
    __shared__ int si[256];
    sv[threadIdx.x] = bv; si[threadIdx.x] = bi;
    __syncthreads();
    for (int s = 128; s > 0; s >>= 1) {
        if (threadIdx.x < (unsigned)s) {
            float ov = sv[threadIdx.x + s]; int oi = si[threadIdx.x + s];
            if (ov > sv[threadIdx.x] || (ov == sv[threadIdx.x] && oi < si[threadIdx.x])) {
                sv[threadIdx.x] = ov; si[threadIdx.x] = oi;
            }
        }
        __syncthreads();
    }
    if (threadIdx.x == 0) target[r] = si[0];
}

// ------------------------------------------------------------------
// Kernel B: acceptance logic + outputs + h gather
__global__ void accept_kernel(const int* __restrict__ target, const int* __restrict__ draft,
                              const int* __restrict__ past_t, const int* __restrict__ slot,
                              const float* __restrict__ hs, int* __restrict__ out,
                              int* __restrict__ tok_ws, float* __restrict__ h_buf) {
    const int b = blockIdx.x;
    __shared__ int s_na;
    if (threadIdx.x == 0) {
        const int* trow = target + b * K1;
        const int* drow = draft + b * K;
        int na = 1, prod = 1;
        for (int k = 0; k < K; ++k) { prod *= (drow[k] == trow[k]) ? 1 : 0; na += prod; }
        s_na = na;
        out[OUT_NA + b] = na;
        int srow = slot[b];
        for (int jj = 0; jj < K; ++jj) {
            int idx = na + jj;
            int v = (idx < K) ? past_t[srow * K + idx] : trow[idx - K];
            out[OUT_NPT + b * K + jj] = v;
        }
        int tok0 = trow[na - 1];
        out[OUT_NNT + b * K1 + 0] = tok0;
        tok_ws[b] = tok0;
        for (int i = 0; i < K1; ++i) out[OUT_ACC + b * K1 + i] = trow[i];
    }
    __syncthreads();
    const int na = s_na;
    const float4* src = (const float4*)(hs + ((size_t)b * K1 + (na - 1)) * H);
    float4* dst = (float4*)(h_buf + (size_t)b * H);
    for (int k = threadIdx.x; k < H / 4; k += 256) dst[k] = src[k];
}

// ------------------------------------------------------------------
// Kernel C1: rms scales for both halves; also init thrInt/resKey/gcnt for this step.
__global__ void rms_scale_kernel(const int* __restrict__ tok_ws, const float* __restrict__ embed,
                                 const float* __restrict__ h_src, float* __restrict__ scales,
                                 unsigned int* __restrict__ thrInt, unsigned long long* __restrict__ resKey,
                                 int* __restrict__ gcnt) {
    const int b = blockIdx.x, tid = threadIdx.x;
    const int tok = tok_ws[b];
    const float4* e4 = (const float4*)(embed + (size_t)tok * H);
    const float4* h4 = (const float4*)(h_src + (size_t)b * H);
    float se = 0.f, sh = 0.f;
#pragma unroll
    for (int r = 0; r < 4; ++r) {
        float4 e = e4[tid + r * 256];
        float4 h = h4[tid + r * 256];
        se += e.x * e.x + e.y * e.y + e.z * e.z + e.w * e.w;
        sh += h.x * h.x + h.y * h.y + h.z * h.z + h.w * h.w;
    }
    __shared__ float r1[256], r2[256];
    r1[tid] = se; r2[tid] = sh;
    __syncthreads();
    for (int s = 128; s > 0; s >>= 1) {
        if (tid < (unsigned)s) { r1[tid] += r1[tid + s]; r2[tid] += r2[tid + s]; }
        __syncthreads();
    }
    if (tid == 0) {
        scales[b]      = 1.0f / sqrtf(r1[0] * (1.0f / H) + 1e-6f);
        scales[64 + b] = 1.0f / sqrtf(r2[0] * (1.0f / H) + 1e-6f);
        thrInt[b] = 0u;
        resKey[b] = 0ull;
        if (b == 0) *gcnt = 0;
    }
}

// ------------------------------------------------------------------
// Kernel C2: build u 3-way bf16 split directly in MFMA-B-fragment layout.
__global__ __launch_bounds__(256) void build_uf_kernel(const int* __restrict__ tok_ws, const float* __restrict__ embed,
                                                       const float* __restrict__ h_src, const float* __restrict__ scales,
                                                       unsigned short* __restrict__ uf) {
    const int c = blockIdx.x;           // 0..255 (p-chunk of 32)
    const int tid = threadIdx.x;
    const int g = tid >> 6, l = tid & 63;
    const int g4 = l >> 4, li = l & 15;
    const int b = g * 16 + li;
    unsigned short h0[8], h1[8], h2[8];
    const float* src;
    float sc;
    if (c < H / 32) { src = embed + (size_t)tok_ws[b] * H + c * 32; sc = scales[b]; }
    else            { src = h_src + (size_t)b * H + (c - H / 32) * 32; sc = scales[64 + b]; }
#pragma unroll
    for (int i = 0; i < 8; ++i) {
        const float a = src[8 * g4 + i] * sc;
        const unsigned short hh = f2bf(a);
        const float r = a - bf2f(hh);
        const unsigned short mm = f2bf(r);
        const float r2 = r - bf2f(mm);
        h0[i] = hh; h1[i] = mm; h2[i] = f2bf(r2);
    }
    unsigned short* dst = uf + (size_t)(((c * 4 + g) * 3) * 64 + l) * 8;
    *(uint4*)(dst)        = mku4(h0);
    *(uint4*)(dst + 512)  = mku4(h1);
    *(uint4*)(dst + 1024) = mku4(h2);
}

// ------------------------------------------------------------------
// Kernel D: GEMM1 via split-bf16 MFMA (6 passes, near-fp32-exact). ks = 8 splits of 1024.
__global__ __launch_bounds__(256) void gemm1_mfma(const float* __restrict__ W,
                                                  const unsigned short* __restrict__ uf,
                                                  float* __restrict__ part) {
    const int tid = threadIdx.x, lane = tid & 63, w = tid >> 6;
    const int bx = blockIdx.x;
    const int ks = blockIdx.y;             // 0..7
    const int vc0 = bx * 8 + w * 2;
    const int g4 = lane >> 4, li = lane & 15;
    const int kbase = ks * 1024;

    const bf16x8_t* Bu = (const bf16x8_t*)uf;
    const f32x4_t z = {0.f, 0.f, 0.f, 0.f};
    f32x4_t acc[2][4];
#pragma unroll
    for (int v2 = 0; v2 < 2; ++v2)
#pragma unroll
        for (int bc = 0; bc < 4; ++bc) acc[v2][bc] = z;

    const float* Wb = W + (size_t)(kbase + 8 * g4) * H + vc0 * 16 + li;

    float acur[2][8], anxt[2][8];
#pragma unroll
    for (int v2 = 0; v2 < 2; ++v2)
#pragma unroll
        for (int i = 0; i < 8; ++i) acur[v2][i] = Wb[(size_t)i * H + v2 * 16];

    for (int c = 0; c < 32; ++c) {
        const int cg = ks * 32 + c;
        bf16x8_t br[12];
#pragma unroll
        for (int f = 0; f < 12; ++f) br[f] = Bu[((size_t)cg * 12 + f) * 64 + lane];
        if (c + 1 < 32) {
#pragma unroll
            for (int v2 = 0; v2 < 2; ++v2)
#pragma unroll
                for (int i = 0; i < 8; ++i) anxt[v2][i] = Wb[(size_t)((c + 1) * 32 + i) * H + v2 * 16];
        }
        bf16x8_t A0[2], A1[2], A2[2];
#pragma unroll
        for (int v2 = 0; v2 < 2; ++v2) {
            unsigned short s0[8], s1[8], s2[8];
#pragma unroll
            for (int i = 0; i < 8; ++i) {
                const float a = acur[v2][i];
                const unsigned short hh = f2bf(a);
                const float r = a - bf2f(hh);
                const unsigned short mm = f2bf(r);
                const float r2 = r - bf2f(mm);
                s0[i] = hh; s1[i] = mm; s2[i] = f2bf(r2);
            }
            A0[v2] = mkfrag(s0); A1[v2] = mkfrag(s1); A2[v2] = mkfrag(s2);
        }
#pragma unroll
        for (int v2 = 0; v2 < 2; ++v2) {
#pragma unroll
            for (int bc = 0; bc < 4; ++bc) {
                f32x4_t t = acc[v2][bc];
                t = __builtin_amdgcn_mfma_f32_16x16x32_bf16(A0[v2], br[bc * 3 + 0], t, 0, 0, 0);
                t = __builtin_amdgcn_mfma_f32_16x16x32_bf16(A0[v2], br[bc * 3 + 1], t, 0, 0, 0);
                t = __builtin_amdgcn_mfma_f32_16x16x32_bf16(A1[v2], br[bc * 3 + 0], t, 0, 0, 0);
                t = __builtin_amdgcn_mfma_f32_16x16x32_bf16(A0[v2], br[bc * 3 + 2], t, 0, 0, 0);
                t = __builtin_amdgcn_mfma_f32_16x16x32_bf16(A1[v2], br[bc * 3 + 1], t, 0, 0, 0);
                t = __builtin_amdgcn_mfma_f32_16x16x32_bf16(A2[v2], br[bc * 3 + 0], t, 0, 0, 0);
                acc[v2][bc] = t;
            }
        }
#pragma unroll
        for (int v2 = 0; v2 < 2; ++v2)
#pragma unroll
            for (int i = 0; i < 8; ++i) acur[v2][i] = anxt[v2][i];
    }
#pragma unroll
    for (int v2 = 0; v2 < 2; ++v2) {
        const int obase = (vc0 + v2) * 16 + g4 * 4;
#pragma unroll
        for (int bc = 0; bc < 4; ++bc)
#pragma unroll
            for (int r = 0; r < 4; ++r)
                part[((size_t)ks * H + obase + r) * B + bc * 16 + li] = acc[v2][bc][r];
    }
}

// ------------------------------------------------------------------
// Kernel E: reduce 8 gemm1 partials -> x_row [b][h] AND xf (fp8 B-frag layout, x*16).
__global__ __launch_bounds__(256) void reduce1_fused(const float* __restrict__ part, float* __restrict__ x_row,
                                                     unsigned long long* __restrict__ xf8) {
    const int kc = blockIdx.x;          // 0..127 (h-chunk of 32)
    const int tid = threadIdx.x;
    const int g = tid >> 6, l = tid & 63;
    const int g4 = l >> 4, li = l & 15;
    const int b = g * 16 + li;
    __shared__ float X[32][65];
    float sv[8];
#pragma unroll
    for (int i = 0; i < 8; ++i) {
        const int o = kc * 32 + 8 * g4 + i;
        float s = 0.f;
#pragma unroll
        for (int ks = 0; ks < 8; ++ks) s += part[((size_t)ks * H + o) * B + b];
        sv[i] = s;
        X[8 * g4 + i][b] = s;
    }
    float svs[8];
#pragma unroll
    for (int i = 0; i < 8; ++i) svs[i] = sv[i] * FP8SCALE;
    xf8[(size_t)(kc * 4 + g) * 64 + l] = pack8fp8(svs);
    __syncthreads();
    const int b2 = tid >> 2, oq = tid & 3;
    float4 o0, o1;
    o0.x = X[oq * 8 + 0][b2]; o0.y = X[oq * 8 + 1][b2]; o0.z = X[oq * 8 + 2][b2]; o0.w = X[oq * 8 + 3][b2];
    o1.x = X[oq * 8 + 4][b2]; o1.y = X[oq * 8 + 5][b2]; o1.z = X[oq * 8 + 6][b2]; o1.w = X[oq * 8 + 7][b2];
    float* dst = x_row + (size_t)b2 * H + kc * 32 + oq * 8;
    *(float4*)(dst) = o0;
    *(float4*)(dst + 4) = o1;
}

// ------------------------------------------------------------------
// Emission helper logic shared by both gemm2 kernels (macro-free, inlined):
// after acc (true units) known: per-b block max -> thrInt atomicMax + bm[]; then every
// value >= bm[b]-DELTA emitted to global list (LDS staged, one global atomicAdd per block).
// Superset property: global candidates (v >= gmax-DELTA) always satisfy v >= bmax-DELTA.

// Kernel F0 (step 0 only): GEMM2 reading fp32 lm_head, converting in-register to fp8 (x16),
// WRITING Lf8 for steps 1-2, emitting candidates. acc is (16x)*(16x) = 256x true.
__global__ __launch_bounds__(256) void gemm2_mfma_first(const float* __restrict__ L,
                                                        const unsigned long long* __restrict__ xf8,
                                                        unsigned long long* __restrict__ Lf8,
                                                        unsigned int* __restrict__ thrInt,
                                                        int* __restrict__ gcnt,
                                                        uint2* __restrict__ glist) {
    const int tid = threadIdx.x, lane = tid & 63, w = tid >> 6;
    const int vc = blockIdx.x * 4 + w;
    const int g4 = lane >> 4, li = lane & 15;
    const float* Lbase = L + (size_t)(vc * 16 + li) * H + 8 * g4;

    const f32x4_t z = {0.f, 0.f, 0.f, 0.f};
    f32x4_t acc[4];
#pragma unroll
    for (int g = 0; g < 4; ++g) acc[g] = z;

    float4 arf[4][2];
    unsigned long long br[4][4];
#pragma unroll
    for (int d = 0; d < 4; ++d) {
        arf[d][0] = *(const float4*)(Lbase + d * 32);
        arf[d][1] = *(const float4*)(Lbase + d * 32 + 4);
#pragma unroll
        for (int g = 0; g < 4; ++g) br[d][g] = xf8[(size_t)(d * 4 + g) * 64 + lane];
    }

    for (int kc = 0; kc < 128; kc += 4) {
#pragma unroll
        for (int d = 0; d < 4; ++d) {
            const float av[8] = {arf[d][0].x * FP8SCALE, arf[d][0].y * FP8SCALE,
                                 arf[d][0].z * FP8SCALE, arf[d][0].w * FP8SCALE,
                                 arf[d][1].x * FP8SCALE, arf[d][1].y * FP8SCALE,
                                 arf[d][1].z * FP8SCALE, arf[d][1].w * FP8SCALE};
            const unsigned long long afrag = pack8fp8(av);
            Lf8[((size_t)vc * 128 + (kc + d)) * 64 + lane] = afrag;
#pragma unroll
            for (int g = 0; g < 4; ++g)
                acc[g] = __builtin_amdgcn_mfma_f32_16x16x32_fp8_fp8((i64_t)afrag, (i64_t)br[d][g], acc[g], 0, 0, 0);
            const int nk = kc + 4 + d;
            if (nk < 128) {
                arf[d][0] = *(const float4*)(Lbase + nk * 32);
                arf[d][1] = *(const float4*)(Lbase + nk * 32 + 4);
#pragma unroll
                for (int g = 0; g < 4; ++g) br[d][g] = xf8[(size_t)(nk * 4 + g) * 64 + lane];
            }
        }
    }

    float m[4];
#pragma unroll
    for (int g = 0; g < 4; ++g) {
#pragma unroll
        for (int r = 0; r < 4; ++r) acc[g][r] *= INVACC;
        m[g] = fmaxf(fmaxf(acc[g][0], acc[g][1]), fmaxf(acc[g][2], acc[g][3]));
        m[g] = fmaxf(m[g], __shfl_xor(m[g], 16));
        m[g] = fmaxf(m[g], __shfl_xor(m[g], 32));
    }
    __shared__ float sm[4][4][16];
    __shared__ float bm[64];
    __shared__ uint2 stage[CAPB];
    __shared__ int lcnt, sbase;
    if (tid == 0) lcnt = 0;
    if (lane < 16) {
#pragma unroll
        for (int g = 0; g < 4; ++g) sm[w][g][lane] = m[g];
    }
    __syncthreads();
    if (tid < 64) {
        const int gg = tid >> 4, ii = tid & 15;
        const float mm = fmaxf(fmaxf(sm[0][gg][ii], sm[1][gg][ii]), fmaxf(sm[2][gg][ii], sm[3][gg][ii]));
        bm[tid] = mm;
        atomicMax(&thrInt[tid], fkey(mm));
    }
    __syncthreads();
#pragma unroll
    for (int g = 0; g < 4; ++g) {
        const int b = g * 16 + li;
        const float thrB = bm[b] - DELTA;
#pragma unroll
        for (int r = 0; r < 4; ++r) {
            const float val = acc[g][r];
            if (val >= thrB) {
                const int v = vc * 16 + g4 * 4 + r;
                const uint2 e = make_uint2(__float_as_uint(val), ((unsigned)b << 16) | (unsigned)v);
                const int s = atomicAdd(&lcnt, 1);
                if (s < CAPB) stage[s] = e;
                else { const int gs = atomicAdd(gcnt, 1); if (gs < CAPG) glist[gs] = e; }
            }
        }
    }
    __syncthreads();
    const int n = min(lcnt, CAPB);
    if (tid == 0) sbase = atomicAdd(gcnt, n);
    __syncthreads();
    for (int i = tid; i < n; i += 256)
        if (sbase + i < CAPG) glist[sbase + i] = stage[i];
}

// ------------------------------------------------------------------
// Kernel F (steps 1-2): GEMM2 from Lf8 (fp8); emit candidates.
__global__ __launch_bounds__(256) void gemm2_mfma(const unsigned long long* __restrict__ Lf8,
                                                  const unsigned long long* __restrict__ xf8,
                                                  unsigned int* __restrict__ thrInt,
                                                  int* __restrict__ gcnt,
                                                  uint2* __restrict__ glist) {
    const int tid = threadIdx.x, lane = tid & 63, w = tid >> 6;
    const int vc = blockIdx.x * 4 + w;
    const int g4 = lane >> 4, li = lane & 15;
    const size_t aBase = (size_t)vc * 128 * 64 + lane;

    const f32x4_t z = {0.f, 0.f, 0.f, 0.f};
    f32x4_t acc[4];
#pragma unroll
    for (int g = 0; g < 4; ++g) acc[g] = z;

    unsigned long long ar[4];
    unsigned long long br[4][4];
#pragma unroll
    for (int d = 0; d < 4; ++d) {
        ar[d] = Lf8[aBase + (size_t)d * 64];
#pragma unroll
        for (int g = 0; g < 4; ++g) br[d][g] = xf8[(size_t)(d * 4 + g) * 64 + lane];
    }

    for (int kc = 0; kc < 128; kc += 4) {
#pragma unroll
        for (int d = 0; d < 4; ++d) {
#pragma unroll
            for (int g = 0; g < 4; ++g)
                acc[g] = __builtin_amdgcn_mfma_f32_16x16x32_fp8_fp8((i64_t)ar[d], (i64_t)br[d][g], acc[g], 0, 0, 0);
            const int nk = kc + 4 + d;
            if (nk < 128) {
                ar[d] = Lf8[aBase + (size_t)nk * 64];
#pragma unroll
                for (int g = 0; g < 4; ++g) br[d][g] = xf8[(size_t)(nk * 4 + g) * 64 + lane];
            }
        }
    }

    float m[4];
#pragma unroll
    for (int g = 0; g < 4; ++g) {
#pragma unroll
        for (int r = 0; r < 4; ++r) acc[g][r] *= INVACC;
        m[g] = fmaxf(fmaxf(acc[g][0], acc[g][1]), fmaxf(acc[g][2], acc[g][3]));
        m[g] = fmaxf(m[g], __shfl_xor(m[g], 16));
        m[g] = fmaxf(m[g], __shfl_xor(m[g], 32));
    }
    __shared__ float sm[4][4][16];
    __shared__ float bm[64];
    __shared__ uint2 stage[CAPB];
    __shared__ int lcnt, sbase;
    if (tid == 0) lcnt = 0;
    if (lane < 16) {
#pragma unroll
        for (int g = 0; g < 4; ++g) sm[w][g][lane] = m[g];
    }
    __syncthreads();
    if (tid < 64) {
        const int gg = tid >> 4, ii = tid & 15;
        const float mm = fmaxf(fmaxf(sm[0][gg][ii], sm[1][gg][ii]), fmaxf(sm[2][gg][ii], sm[3][gg][ii]));
        bm[tid] = mm;
        atomicMax(&thrInt[tid], fkey(mm));
    }
    __syncthreads();
#pragma unroll
    for (int g = 0; g < 4; ++g) {
        const int b = g * 16 + li;
        const float thrB = bm[b] - DELTA;
#pragma unroll
        for (int r = 0; r < 4; ++r) {
            const float val = acc[g][r];
            if (val >= thrB) {
                const int v = vc * 16 + g4 * 4 + r;
                const uint2 e = make_uint2(__float_as_uint(val), ((unsigned)b << 16) | (unsigned)v);
                const int s = atomicAdd(&lcnt, 1);
                if (s < CAPB) stage[s] = e;
                else { const int gs = atomicAdd(gcnt, 1); if (gs < CAPG) glist[gs] = e; }
            }
        }
    }
    __syncthreads();
    const int n = min(lcnt, CAPB);
    if (tid == 0) sbase = atomicAdd(gcnt, n);
    __syncthreads();
    for (int i = tid; i < n; i += 256)
        if (sbase + i < CAPG) glist[sbase + i] = stage[i];
}

// ------------------------------------------------------------------
// Kernel R: filter candidates vs global threshold, exact fp32 rescore, atomic argmax.
__global__ __launch_bounds__(256) void rescore_kernel(const uint2* __restrict__ glist,
                                                      const int* __restrict__ gcnt,
                                                      const unsigned int* __restrict__ thrInt,
                                                      const float* __restrict__ L,
                                                      const float* __restrict__ x_row,
                                                      unsigned long long* __restrict__ resKey) {
    const int total = min(*gcnt, CAPG);
    const int lane = threadIdx.x & 63, w = threadIdx.x >> 6;
    for (int idx = blockIdx.x * 4 + w; idx < total; idx += gridDim.x * 4) {
        const uint2 e = glist[idx];
        const int b = (int)(e.y >> 16), v = (int)(e.y & 0xFFFFu);
        const float aval = __uint_as_float(e.x);
        if (aval < funkey(thrInt[b]) - DELTA) continue;
        const float* Lr = L + (size_t)v * H;
        const float* xr = x_row + (size_t)b * H;
        float s = 0.f;
#pragma unroll 8
        for (int t = 0; t < 64; ++t) s = fmaf(Lr[lane + 64 * t], xr[lane + 64 * t], s);
#pragma unroll
        for (int off = 32; off >= 1; off >>= 1) s += __shfl_xor(s, off);
        if (lane == 0) {
            const unsigned long long key = ((unsigned long long)fkey(s) << 32) | (unsigned)(~(unsigned)v);
            atomicMax(&resKey[b], key);
        }
    }
}

// ------------------------------------------------------------------
// Kernel FZ: decode resKey -> token; write outputs for step j.
__global__ void finalize_kernel(const unsigned long long* __restrict__ resKey,
                                int* __restrict__ tok_ws, int* __restrict__ out, int j) {
    const int b = threadIdx.x;   // 64
    const int v = (int)(~(unsigned)(resKey[b] & 0xFFFFFFFFull));
    tok_ws[b] = v;
    out[OUT_NDT + b * K + j] = v;
    out[OUT_NNT + b * K1 + 1 + j] = v;
}

// ------------------------------------------------------------------
extern "C" void kernel_launch(void* const* d_in, const int* in_sizes, int n_in,
                              void* d_out, int out_size, void* d_ws, size_t ws_size,
                              hipStream_t stream) {
    const float* logits  = (const float*)d_in[0];
    const float* hs      = (const float*)d_in[1];
    // d_in[2] past_hidden_pool: provably unused (num_accepted >= 1)
    const float* embed   = (const float*)d_in[3];
    const float* lm_head = (const float*)d_in[4];
    const float* mtp_fc  = (const float*)d_in[5];
    const int* draft     = (const int*)d_in[6];
    const int* past_t    = (const int*)d_in[7];
    const int* slot      = (const int*)d_in[8];
    int* out = (int*)d_out;

    char* ws = (char*)d_ws;
    int* target          = (int*)(ws + OFF_TARGET);
    int* tok_ws          = (int*)(ws + OFF_TOK);
    unsigned int* thrInt = (unsigned int*)(ws + OFF_THRI);
    int* gcnt            = (int*)(ws + OFF_GCNT);
    unsigned long long* resKey = (unsigned long long*)(ws + OFF_RESK);
    float* scales        = (float*)(ws + OFF_SCALE);
    float* h_buf         = (float*)(ws + OFF_HBUF);
    float* x_row         = (float*)(ws + OFF_XROW);
    unsigned short* uf   = (unsigned short*)(ws + OFF_UF);
    unsigned long long* xf8 = (unsigned long long*)(ws + OFF_XF);
    float* part          = (float*)(ws + OFF_PART);
    uint2* glist         = (uint2*)(ws + OFF_PART);   // reuses part space (dead after reduce1)
    unsigned long long* Lf8 = (unsigned long long*)(ws + OFF_LF);

    argmax_logits_kernel<<<B * K1, 256, 0, stream>>>(logits, target);
    accept_kernel<<<B, 256, 0, stream>>>(target, draft, past_t, slot, hs, out, tok_ws, h_buf);

    for (int j = 0; j < K; ++j) {
        const float* h_src = (j == 0) ? h_buf : x_row;
        rms_scale_kernel<<<B, 256, 0, stream>>>(tok_ws, embed, h_src, scales, thrInt, resKey, gcnt);
        build_uf_kernel<<<2 * H / 32, 256, 0, stream>>>(tok_ws, embed, h_src, scales, uf);
        gemm1_mfma<<<dim3(32, 8), 256, 0, stream>>>(mtp_fc + (size_t)j * 2 * H * H, uf, part);
        reduce1_fused<<<H / 32, 256, 0, stream>>>(part, x_row, xf8);
        if (j == 0)
            gemm2_mfma_first<<<V / 64, 256, 0, stream>>>(lm_head, xf8, Lf8, thrInt, gcnt, glist);
        else
            gemm2_mfma<<<V / 64, 256, 0, stream>>>(Lf8, xf8, thrInt, gcnt, glist);
        rescore_kernel<<<256, 256, 0, stream>>>(glist, gcnt, thrInt, lm_head, x_row, resKey);
        finalize_kernel<<<1, 64, 0, stream>>>(resKey, tok_ws, out, j);
    }
}

// Round 13
// 581.544 us; speedup vs baseline: 1.1443x; 1.1443x over previous
//
#include <hip/hip_runtime.h>
#include <hip/hip_bf16.h>
#include <math.h>

#define B 64
#define K 3
#define H 4096
#define V 32000
#define K1 (K + 1)

typedef short bf16x8_t __attribute__((ext_vector_type(8)));
typedef float f32x4_t __attribute__((ext_vector_type(4)));
typedef long long i64_t;

// ---------------- workspace layout (bytes) ----------------
#define OFF_TARGET  0                      // 256 int
#define OFF_TOK     1024                   // 64 int
#define OFF_THRI    2048                   // 64 uint
#define OFF_RESK    4096                   // 64 ull (8B aligned)
#define OFF_SCALE   8192                   // 128 float
#define OFF_HBUF    (1u << 20)             // B*H float (1 MB)
#define OFF_XROW    (2u << 20)             // B*H float, x row-major [b][h]
#define OFF_UF      (3u << 20)             // u 3-way bf16 split frags (3 MB)
#define OFF_XF      (6u << 20)             // x fp8 frag layout (256 KB)
#define OFF_DLOGA   (7u << 20)             // V*B ushort (bf16) approx logits (4.1 MB)
#define OFF_PART    (16u << 20)            // 16 ks * H * B float = 16.8 MB
#define OFF_LF      (48u << 20)            // lm_head fp8 frag layout (131 MB)

// out layout: accepted[256] | num_accepted[64] | next_draft[192] | next_new[256] | new_past_t[192]
#define OUT_ACC 0
#define OUT_NA  256
#define OUT_NDT 320
#define OUT_NNT 512
#define OUT_NPT 768

#define DELTA 1.5f
#define FP8SCALE 16.0f
#define INVACC (1.0f / 256.0f)

__device__ __forceinline__ unsigned short f2bf(float f) {
    unsigned int u = __float_as_uint(f);
    u += 0x7fffu + ((u >> 16) & 1u);       // round-to-nearest-even
    return (unsigned short)(u >> 16);
}
__device__ __forceinline__ float bf2f(unsigned short h) {
    return __uint_as_float(((unsigned int)h) << 16);
}
__device__ __forceinline__ uint4 mku4(const unsigned short* p) {
    return make_uint4((unsigned)p[0] | ((unsigned)p[1] << 16),
                      (unsigned)p[2] | ((unsigned)p[3] << 16),
                      (unsigned)p[4] | ((unsigned)p[5] << 16),
                      (unsigned)p[6] | ((unsigned)p[7] << 16));
}
__device__ __forceinline__ bf16x8_t mkfrag(const unsigned short* p) {
    union { uint4 q; bf16x8_t v; } u;
    u.q = mku4(p);
    return u.v;
}
// monotonic float<->uint key (larger float => larger key); all-zero init < every valid key
__device__ __forceinline__ unsigned fkey(float f) {
    unsigned u = __float_as_uint(f);
    return u ^ ((unsigned)((int)u >> 31) | 0x80000000u);
}
__device__ __forceinline__ float funkey(unsigned k) {
    unsigned u = (k & 0x80000000u) ? (k ^ 0x80000000u) : ~k;
    return __uint_as_float(u);
}
// fp32 -> OCP e4m3fn, round-to-nearest-even, saturate at 448, subnormals handled.
__device__ __forceinline__ unsigned int f2fp8(float f) {
    unsigned u = __float_as_uint(f);
    unsigned sgn = (u >> 24) & 0x80u;
    unsigned au = u & 0x7FFFFFFFu;
    if (au >= 0x43E00000u) return sgn | 0x7Eu;            // clamp to +-448
    if (au < 0x3C800000u) {                               // |f| < 2^-6: subnormal
        float a = __uint_as_float(au);
        int m = (int)rintf(a * 512.0f);                   // steps of 2^-9; m==8 -> min normal
        return sgn | (unsigned)m;
    }
    unsigned r = au + 0x7FFFFu + ((au >> 20) & 1u);       // RNE at 3 mantissa bits
    unsigned e = (r >> 23) - 120u;
    unsigned m = (r >> 20) & 7u;
    return sgn | (e << 3) | m;
}
// pack 8 floats (pre-scaled) into one fp8x8 (i64)
__device__ __forceinline__ unsigned long long pack8fp8(const float* a) {
    unsigned lo = f2fp8(a[0]) | (f2fp8(a[1]) << 8) | (f2fp8(a[2]) << 16) | (f2fp8(a[3]) << 24);
    unsigned hi = f2fp8(a[4]) | (f2fp8(a[5]) << 8) | (f2fp8(a[6]) << 16) | (f2fp8(a[7]) << 24);
    return (unsigned long long)lo | ((unsigned long long)hi << 32);
}

// ------------------------------------------------------------------
// Kernel A: row-wise argmax of logits (256 rows x 32000), first-index tie-break
__global__ void argmax_logits_kernel(const float* __restrict__ logits, int* __restrict__ target) {
    const int r = blockIdx.x;
    const float4* row = (const float4*)(logits + (size_t)r * V);
    float bv = -INFINITY;
    int bi = 0x7fffffff;
    for (int i4 = threadIdx.x; i4 < V / 4; i4 += 256) {
        float4 v = row[i4];
        int base = i4 * 4;
        if (v.x > bv) { bv = v.x; bi = base; }
        if (v.y > bv) { bv = v.y; bi = base + 1; }
        if (v.z > bv) { bv = v.z; bi = base + 2; }
        if (v.w > bv) { bv = v.w; bi = base + 3; }
    }
    __shared__ float sv[256];
    __shared__ int si[256];
    sv[threadIdx.x] = bv; si[threadIdx.x] = bi;
    __syncthreads();
    for (int s = 128; s > 0; s >>= 1) {
        if (threadIdx.x < (unsigned)s) {
            float ov = sv[threadIdx.x + s]; int oi = si[threadIdx.x + s];
            if (ov > sv[threadIdx.x] || (ov == sv[threadIdx.x] && oi < si[threadIdx.x])) {
                sv[threadIdx.x] = ov; si[threadIdx.x] = oi;
            }
        }
        __syncthreads();
    }
    if (threadIdx.x == 0) target[r] = si[0];
}

// ------------------------------------------------------------------
// Kernel B: acceptance logic + outputs + h gather
__global__ void accept_kernel(const int* __restrict__ target, const int* __restrict__ draft,
                              const int* __restrict__ past_t, const int* __restrict__ slot,
                              const float* __restrict__ hs, int* __restrict__ out,
                              int* __restrict__ tok_ws, float* __restrict__ h_buf) {
    const int b = blockIdx.x;
    __shared__ int s_na;
    if (threadIdx.x == 0) {
        const int* trow = target + b * K1;
        const int* drow = draft + b * K;
        int na = 1, prod = 1;
        for (int k = 0; k < K; ++k) { prod *= (drow[k] == trow[k]) ? 1 : 0; na += prod; }
        s_na = na;
        out[OUT_NA + b] = na;
        int srow = slot[b];
        for (int jj = 0; jj < K; ++jj) {
            int idx = na + jj;
            int v = (idx < K) ? past_t[srow * K + idx] : trow[idx - K];
            out[OUT_NPT + b * K + jj] = v;
        }
        int tok0 = trow[na - 1];
        out[OUT_NNT + b * K1 + 0] = tok0;
        tok_ws[b] = tok0;
        for (int i = 0; i < K1; ++i) out[OUT_ACC + b * K1 + i] = trow[i];
    }
    __syncthreads();
    const int na = s_na;
    const float4* src = (const float4*)(hs + ((size_t)b * K1 + (na - 1)) * H);
    float4* dst = (float4*)(h_buf + (size_t)b * H);
    for (int k = threadIdx.x; k < H / 4; k += 256) dst[k] = src[k];
}

// ------------------------------------------------------------------
// Kernel C1: rms scales for both halves; also finalizes PREVIOUS step (decode resKey ->
// token, write outputs for j-1, update tok_ws) and resets thrInt/resKey for this step.
__global__ void rms_scale_kernel(int j, unsigned long long* __restrict__ resKey,
                                 int* __restrict__ out, int* __restrict__ tok_ws,
                                 const float* __restrict__ embed, const float* __restrict__ h_src,
                                 float* __restrict__ scales, unsigned int* __restrict__ thrInt) {
    const int b = blockIdx.x, tid = threadIdx.x;
    int tok;
    if (j == 0) tok = tok_ws[b];
    else        tok = (int)(~(unsigned)(resKey[b] & 0xFFFFFFFFull));
    const float4* e4 = (const float4*)(embed + (size_t)tok * H);
    const float4* h4 = (const float4*)(h_src + (size_t)b * H);
    float se = 0.f, sh = 0.f;
#pragma unroll
    for (int r = 0; r < 4; ++r) {
        float4 e = e4[tid + r * 256];
        float4 h = h4[tid + r * 256];
        se += e.x * e.x + e.y * e.y + e.z * e.z + e.w * e.w;
        sh += h.x * h.x + h.y * h.y + h.z * h.z + h.w * h.w;
    }
    __shared__ float r1[256], r2[256];
    r1[tid] = se; r2[tid] = sh;
    __syncthreads();
    for (int s = 128; s > 0; s >>= 1) {
        if (tid < (unsigned)s) { r1[tid] += r1[tid + s]; r2[tid] += r2[tid + s]; }
        __syncthreads();
    }
    if (tid == 0) {
        scales[b]      = 1.0f / sqrtf(r1[0] * (1.0f / H) + 1e-6f);
        scales[64 + b] = 1.0f / sqrtf(r2[0] * (1.0f / H) + 1e-6f);
        if (j > 0) {
            out[OUT_NDT + b * K + (j - 1)] = tok;
            out[OUT_NNT + b * K1 + j] = tok;
            tok_ws[b] = tok;
        }
        thrInt[b] = 0u;
        resKey[b] = 0ull;
    }
}

// ------------------------------------------------------------------
// Kernel C2: build u 3-way bf16 split directly in MFMA-B-fragment layout.
__global__ __launch_bounds__(256) void build_uf_kernel(const int* __restrict__ tok_ws, const float* __restrict__ embed,
                                                       const float* __restrict__ h_src, const float* __restrict__ scales,
                                                       unsigned short* __restrict__ uf) {
    const int c = blockIdx.x;           // 0..255 (p-chunk of 32)
    const int tid = threadIdx.x;
    const int g = tid >> 6, l = tid & 63;
    const int g4 = l >> 4, li = l & 15;
    const int b = g * 16 + li;
    unsigned short h0[8], h1[8], h2[8];
    const float* src;
    float sc;
    if (c < H / 32) { src = embed + (size_t)tok_ws[b] * H + c * 32; sc = scales[b]; }
    else            { src = h_src + (size_t)b * H + (c - H / 32) * 32; sc = scales[64 + b]; }
#pragma unroll
    for (int i = 0; i < 8; ++i) {
        const float a = src[8 * g4 + i] * sc;
        const unsigned short hh = f2bf(a);
        const float r = a - bf2f(hh);
        const unsigned short mm = f2bf(r);
        const float r2 = r - bf2f(mm);
        h0[i] = hh; h1[i] = mm; h2[i] = f2bf(r2);
    }
    unsigned short* dst = uf + (size_t)(((c * 4 + g) * 3) * 64 + l) * 8;
    *(uint4*)(dst)        = mku4(h0);
    *(uint4*)(dst + 512)  = mku4(h1);
    *(uint4*)(dst + 1024) = mku4(h2);
}

// ------------------------------------------------------------------
// Kernel D: GEMM1 via split-bf16 MFMA (6 passes, near-fp32-exact).
// Reduction dim is 2H = 8192: ks = 16 splits of 512 (16 chunks of 32 each).
__global__ __launch_bounds__(256) void gemm1_mfma(const float* __restrict__ W,
                                                  const unsigned short* __restrict__ uf,
                                                  float* __restrict__ part) {
    const int tid = threadIdx.x, lane = tid & 63, w = tid >> 6;
    const int bx = blockIdx.x;
    const int ks = blockIdx.y;             // 0..15
    const int vc0 = bx * 8 + w * 2;
    const int g4 = lane >> 4, li = lane & 15;
    const int kbase = ks * 512;

    const bf16x8_t* Bu = (const bf16x8_t*)uf;
    const f32x4_t z = {0.f, 0.f, 0.f, 0.f};
    f32x4_t acc[2][4];
#pragma unroll
    for (int v2 = 0; v2 < 2; ++v2)
#pragma unroll
        for (int bc = 0; bc < 4; ++bc) acc[v2][bc] = z;

    const float* Wb = W + (size_t)(kbase + 8 * g4) * H + vc0 * 16 + li;

    float acur[2][8], anxt[2][8];
#pragma unroll
    for (int v2 = 0; v2 < 2; ++v2)
#pragma unroll
        for (int i = 0; i < 8; ++i) acur[v2][i] = Wb[(size_t)i * H + v2 * 16];

    for (int c = 0; c < 16; ++c) {
        const int cg = ks * 16 + c;        // global 32-p chunk index, 0..255
        bf16x8_t br[12];
#pragma unroll
        for (int f = 0; f < 12; ++f) br[f] = Bu[((size_t)cg * 12 + f) * 64 + lane];
        if (c + 1 < 16) {
#pragma unroll
            for (int v2 = 0; v2 < 2; ++v2)
#pragma unroll
                for (int i = 0; i < 8; ++i) anxt[v2][i] = Wb[(size_t)((c + 1) * 32 + i) * H + v2 * 16];
        }
        bf16x8_t A0[2], A1[2], A2[2];
#pragma unroll
        for (int v2 = 0; v2 < 2; ++v2) {
            unsigned short s0[8], s1[8], s2[8];
#pragma unroll
            for (int i = 0; i < 8; ++i) {
                const float a = acur[v2][i];
                const unsigned short hh = f2bf(a);
                const float r = a - bf2f(hh);
                const unsigned short mm = f2bf(r);
                const float r2 = r - bf2f(mm);
                s0[i] = hh; s1[i] = mm; s2[i] = f2bf(r2);
            }
            A0[v2] = mkfrag(s0); A1[v2] = mkfrag(s1); A2[v2] = mkfrag(s2);
        }
#pragma unroll
        for (int v2 = 0; v2 < 2; ++v2) {
#pragma unroll
            for (int bc = 0; bc < 4; ++bc) {
                f32x4_t t = acc[v2][bc];
                t = __builtin_amdgcn_mfma_f32_16x16x32_bf16(A0[v2], br[bc * 3 + 0], t, 0, 0, 0);
                t = __builtin_amdgcn_mfma_f32_16x16x32_bf16(A0[v2], br[bc * 3 + 1], t, 0, 0, 0);
                t = __builtin_amdgcn_mfma_f32_16x16x32_bf16(A1[v2], br[bc * 3 + 0], t, 0, 0, 0);
                t = __builtin_amdgcn_mfma_f32_16x16x32_bf16(A0[v2], br[bc * 3 + 2], t, 0, 0, 0);
                t = __builtin_amdgcn_mfma_f32_16x16x32_bf16(A1[v2], br[bc * 3 + 1], t, 0, 0, 0);
                t = __builtin_amdgcn_mfma_f32_16x16x32_bf16(A2[v2], br[bc * 3 + 0], t, 0, 0, 0);
                acc[v2][bc] = t;
            }
        }
#pragma unroll
        for (int v2 = 0; v2 < 2; ++v2)
#pragma unroll
            for (int i = 0; i < 8; ++i) acur[v2][i] = anxt[v2][i];
    }
#pragma unroll
    for (int v2 = 0; v2 < 2; ++v2) {
        const int obase = (vc0 + v2) * 16 + g4 * 4;
#pragma unroll
        for (int bc = 0; bc < 4; ++bc)
#pragma unroll
            for (int r = 0; r < 4; ++r)
                part[((size_t)ks * H + obase + r) * B + bc * 16 + li] = acc[v2][bc][r];
    }
}

// ------------------------------------------------------------------
// Kernel E: reduce 16 gemm1 partials -> x_row [b][h] AND xf (fp8 B-frag layout, x*16).
__global__ __launch_bounds__(256) void reduce1_fused(const float* __restrict__ part, float* __restrict__ x_row,
                                                     unsigned long long* __restrict__ xf8) {
    const int kc = blockIdx.x;          // 0..127 (h-chunk of 32)
    const int tid = threadIdx.x;
    const int g = tid >> 6, l = tid & 63;
    const int g4 = l >> 4, li = l & 15;
    const int b = g * 16 + li;
    __shared__ float X[32][65];
    float sv[8];
#pragma unroll
    for (int i = 0; i < 8; ++i) {
        const int o = kc * 32 + 8 * g4 + i;
        float s = 0.f;
#pragma unroll
        for (int ks = 0; ks < 16; ++ks) s += part[((size_t)ks * H + o) * B + b];
        sv[i] = s;
        X[8 * g4 + i][b] = s;
    }
    float svs[8];
#pragma unroll
    for (int i = 0; i < 8; ++i) svs[i] = sv[i] * FP8SCALE;
    xf8[(size_t)(kc * 4 + g) * 64 + l] = pack8fp8(svs);
    __syncthreads();
    const int b2 = tid >> 2, oq = tid & 3;
    float4 o0, o1;
    o0.x = X[oq * 8 + 0][b2]; o0.y = X[oq * 8 + 1][b2]; o0.z = X[oq * 8 + 2][b2]; o0.w = X[oq * 8 + 3][b2];
    o1.x = X[oq * 8 + 4][b2]; o1.y = X[oq * 8 + 5][b2]; o1.z = X[oq * 8 + 6][b2]; o1.w = X[oq * 8 + 7][b2];
    float* dst = x_row + (size_t)b2 * H + kc * 32 + oq * 8;
    *(float4*)(dst) = o0;
    *(float4*)(dst + 4) = o1;
}

// ------------------------------------------------------------------
// Kernel F0 (step 0 only): GEMM2 reading fp32 lm_head, converting in-register to fp8 (x16),
// WRITING Lf8 for steps 1-2, computing dlogA (bf16) + atomic per-b max.
__global__ __launch_bounds__(256) void gemm2_mfma_first(const float* __restrict__ L,
                                                        const unsigned long long* __restrict__ xf8,
                                                        unsigned long long* __restrict__ Lf8,
                                                        unsigned short* __restrict__ dlogA,
                                                        unsigned int* __restrict__ thrInt) {
    const int tid = threadIdx.x, lane = tid & 63, w = tid >> 6;
    const int vc = blockIdx.x * 4 + w;
    const int g4 = lane >> 4, li = lane & 15;
    const float* Lbase = L + (size_t)(vc * 16 + li) * H + 8 * g4;

    const f32x4_t z = {0.f, 0.f, 0.f, 0.f};
    f32x4_t acc[4];
#pragma unroll
    for (int g = 0; g < 4; ++g) acc[g] = z;

    float4 arf[4][2];
    unsigned long long br[4][4];
#pragma unroll
    for (int d = 0; d < 4; ++d) {
        arf[d][0] = *(const float4*)(Lbase + d * 32);
        arf[d][1] = *(const float4*)(Lbase + d * 32 + 4);
#pragma unroll
        for (int g = 0; g < 4; ++g) br[d][g] = xf8[(size_t)(d * 4 + g) * 64 + lane];
    }

    for (int kc = 0; kc < 128; kc += 4) {
#pragma unroll
        for (int d = 0; d < 4; ++d) {
            const float av[8] = {arf[d][0].x * FP8SCALE, arf[d][0].y * FP8SCALE,
                                 arf[d][0].z * FP8SCALE, arf[d][0].w * FP8SCALE,
                                 arf[d][1].x * FP8SCALE, arf[d][1].y * FP8SCALE,
                                 arf[d][1].z * FP8SCALE, arf[d][1].w * FP8SCALE};
            const unsigned long long afrag = pack8fp8(av);
            Lf8[((size_t)vc * 128 + (kc + d)) * 64 + lane] = afrag;
#pragma unroll
            for (int g = 0; g < 4; ++g)
                acc[g] = __builtin_amdgcn_mfma_f32_16x16x32_fp8_fp8((i64_t)afrag, (i64_t)br[d][g], acc[g], 0, 0, 0);
            const int nk = kc + 4 + d;
            if (nk < 128) {
                arf[d][0] = *(const float4*)(Lbase + nk * 32);
                arf[d][1] = *(const float4*)(Lbase + nk * 32 + 4);
#pragma unroll
                for (int g = 0; g < 4; ++g) br[d][g] = xf8[(size_t)(nk * 4 + g) * 64 + lane];
            }
        }
    }

    float m[4];
#pragma unroll
    for (int g = 0; g < 4; ++g) {
#pragma unroll
        for (int r = 0; r < 4; ++r) acc[g][r] *= INVACC;
        m[g] = fmaxf(fmaxf(acc[g][0], acc[g][1]), fmaxf(acc[g][2], acc[g][3]));
        m[g] = fmaxf(m[g], __shfl_xor(m[g], 16));
        m[g] = fmaxf(m[g], __shfl_xor(m[g], 32));
    }
#pragma unroll
    for (int g = 0; g < 4; ++g) {
        const int vbase = vc * 16 + g4 * 4;
#pragma unroll
        for (int r = 0; r < 4; ++r)
            dlogA[(size_t)(vbase + r) * B + g * 16 + li] = f2bf(acc[g][r]);
    }
    __shared__ float sm[4][4][16];
    if (lane < 16) {
#pragma unroll
        for (int g = 0; g < 4; ++g) sm[w][g][lane] = m[g];
    }
    __syncthreads();
    if (tid < 64) {
        const int gg = tid >> 4, ii = tid & 15;
        const float mm = fmaxf(fmaxf(sm[0][gg][ii], sm[1][gg][ii]), fmaxf(sm[2][gg][ii], sm[3][gg][ii]));
        atomicMax(&thrInt[tid], fkey(mm));
    }
}

// ------------------------------------------------------------------
// Kernel F (steps 1-2): GEMM2 from Lf8 (fp8); dlogA (bf16) + atomic per-b max.
__global__ __launch_bounds__(256) void gemm2_mfma(const unsigned long long* __restrict__ Lf8,
                                                  const unsigned long long* __restrict__ xf8,
                                                  unsigned short* __restrict__ dlogA,
                                                  unsigned int* __restrict__ thrInt) {
    const int tid = threadIdx.x, lane = tid & 63, w = tid >> 6;
    const int vc = blockIdx.x * 4 + w;
    const size_t aBase = (size_t)vc * 128 * 64 + lane;

    const f32x4_t z = {0.f, 0.f, 0.f, 0.f};
    f32x4_t acc[4];
#pragma unroll
    for (int g = 0; g < 4; ++g) acc[g] = z;

    unsigned long long ar[4];
    unsigned long long br[4][4];
#pragma unroll
    for (int d = 0; d < 4; ++d) {
        ar[d] = Lf8[aBase + (size_t)d * 64];
#pragma unroll
        for (int g = 0; g < 4; ++g) br[d][g] = xf8[(size_t)(d * 4 + g) * 64 + lane];
    }

    for (int kc = 0; kc < 128; kc += 4) {
#pragma unroll
        for (int d = 0; d < 4; ++d) {
#pragma unroll
            for (int g = 0; g < 4; ++g)
                acc[g] = __builtin_amdgcn_mfma_f32_16x16x32_fp8_fp8((i64_t)ar[d], (i64_t)br[d][g], acc[g], 0, 0, 0);
            const int nk = kc + 4 + d;
            if (nk < 128) {
                ar[d] = Lf8[aBase + (size_t)nk * 64];
#pragma unroll
                for (int g = 0; g < 4; ++g) br[d][g] = xf8[(size_t)(nk * 4 + g) * 64 + lane];
            }
        }
    }

    const int li = lane & 15, g4 = lane >> 4;
    float m[4];
#pragma unroll
    for (int g = 0; g < 4; ++g) {
#pragma unroll
        for (int r = 0; r < 4; ++r) acc[g][r] *= INVACC;
        m[g] = fmaxf(fmaxf(acc[g][0], acc[g][1]), fmaxf(acc[g][2], acc[g][3]));
        m[g] = fmaxf(m[g], __shfl_xor(m[g], 16));
        m[g] = fmaxf(m[g], __shfl_xor(m[g], 32));
    }
#pragma unroll
    for (int g = 0; g < 4; ++g) {
        const int vbase = vc * 16 + g4 * 4;
#pragma unroll
        for (int r = 0; r < 4; ++r)
            dlogA[(size_t)(vbase + r) * B + g * 16 + li] = f2bf(acc[g][r]);
    }
    __shared__ float sm[4][4][16];
    if (lane < 16) {
#pragma unroll
        for (int g = 0; g < 4; ++g) sm[w][g][lane] = m[g];
    }
    __syncthreads();
    if (tid < 64) {
        const int gg = tid >> 4, ii = tid & 15;
        const float mm = fmaxf(fmaxf(sm[0][gg][ii], sm[1][gg][ii]), fmaxf(sm[2][gg][ii], sm[3][gg][ii]));
        atomicMax(&thrInt[tid], fkey(mm));
    }
}

// ------------------------------------------------------------------
// Kernel CR: fused collect + exact fp32 rescore + deterministic atomic argmax.
// resKey[b] = max over candidates of (fkey(exact_val) << 32 | ~v)  -> order-independent.
__global__ __launch_bounds__(256) void collect_rescore(const unsigned short* __restrict__ dlogA,
                                                       const unsigned int* __restrict__ thrInt,
                                                       const float* __restrict__ L,
                                                       const float* __restrict__ x_row,
                                                       unsigned long long* __restrict__ resKey) {
    const int v0 = blockIdx.x * 256;
    __shared__ int s_cnt;
    __shared__ int s_v[512];
    __shared__ int s_b[512];
    if (threadIdx.x == 0) s_cnt = 0;
    __syncthreads();
    for (int i = threadIdx.x; i < 256 * 64; i += 256) {
        const int vl = i >> 6, b = i & 63;
        const float val = bf2f(dlogA[(size_t)(v0 + vl) * B + b]);
        const float thr = funkey(thrInt[b]) - DELTA;
        if (val >= thr) {
            const int s = atomicAdd(&s_cnt, 1);
            if (s < 512) { s_v[s] = v0 + vl; s_b[s] = b; }
        }
    }
    __syncthreads();
    const int n = min(s_cnt, 512);
    const int lane = threadIdx.x & 63, w = threadIdx.x >> 6;
    for (int c = w; c < n; c += 4) {
        const int v = s_v[c], b = s_b[c];
        const float* Lr = L + (size_t)v * H;
        const float* xr = x_row + (size_t)b * H;
        float s = 0.f;
#pragma unroll 8
        for (int t = 0; t < 64; ++t) s = fmaf(Lr[lane + 64 * t], xr[lane + 64 * t], s);
#pragma unroll
        for (int off = 32; off >= 1; off >>= 1) s += __shfl_xor(s, off);
        if (lane == 0) {
            const unsigned long long key = ((unsigned long long)fkey(s) << 32) | (unsigned)(~(unsigned)v);
            atomicMax(&resKey[b], key);
        }
    }
}

// ------------------------------------------------------------------
// Kernel FZ: decode resKey -> token; write outputs for the LAST step only.
__global__ void finalize_kernel(const unsigned long long* __restrict__ resKey,
                                int* __restrict__ out, int j) {
    const int b = threadIdx.x;   // 64
    const int v = (int)(~(unsigned)(resKey[b] & 0xFFFFFFFFull));
    out[OUT_NDT + b * K + j] = v;
    out[OUT_NNT + b * K1 + 1 + j] = v;
}

// ------------------------------------------------------------------
extern "C" void kernel_launch(void* const* d_in, const int* in_sizes, int n_in,
                              void* d_out, int out_size, void* d_ws, size_t ws_size,
                              hipStream_t stream) {
    const float* logits  = (const float*)d_in[0];
    const float* hs      = (const float*)d_in[1];
    // d_in[2] past_hidden_pool: provably unused (num_accepted >= 1)
    const float* embed   = (const float*)d_in[3];
    const float* lm_head = (const float*)d_in[4];
    const float* mtp_fc  = (const float*)d_in[5];
    const int* draft     = (const int*)d_in[6];
    const int* past_t    = (const int*)d_in[7];
    const int* slot      = (const int*)d_in[8];
    int* out = (int*)d_out;

    char* ws = (char*)d_ws;
    int* target          = (int*)(ws + OFF_TARGET);
    int* tok_ws          = (int*)(ws + OFF_TOK);
    unsigned int* thrInt = (unsigned int*)(ws + OFF_THRI);
    unsigned long long* resKey = (unsigned long long*)(ws + OFF_RESK);
    float* scales        = (float*)(ws + OFF_SCALE);
    float* h_buf         = (float*)(ws + OFF_HBUF);
    float* x_row         = (float*)(ws + OFF_XROW);
    unsigned short* uf   = (unsigned short*)(ws + OFF_UF);
    unsigned long long* xf8 = (unsigned long long*)(ws + OFF_XF);
    unsigned short* dlogA = (unsigned short*)(ws + OFF_DLOGA);
    float* part          = (float*)(ws + OFF_PART);
    unsigned long long* Lf8 = (unsigned long long*)(ws + OFF_LF);

    argmax_logits_kernel<<<B * K1, 256, 0, stream>>>(logits, target);
    accept_kernel<<<B, 256, 0, stream>>>(target, draft, past_t, slot, hs, out, tok_ws, h_buf);

    for (int j = 0; j < K; ++j) {
        const float* h_src = (j == 0) ? h_buf : x_row;
        rms_scale_kernel<<<B, 256, 0, stream>>>(j, resKey, out, tok_ws, embed, h_src, scales, thrInt);
        build_uf_kernel<<<2 * H / 32, 256, 0, stream>>>(tok_ws, embed, h_src, scales, uf);
        gemm1_mfma<<<dim3(32, 16), 256, 0, stream>>>(mtp_fc + (size_t)j * 2 * H * H, uf, part);
        reduce1_fused<<<H / 32, 256, 0, stream>>>(part, x_row, xf8);
        if (j == 0)
            gemm2_mfma_first<<<V / 64, 256, 0, stream>>>(lm_head, xf8, Lf8, dlogA, thrInt);
        else
            gemm2_mfma<<<V / 64, 256, 0, stream>>>(Lf8, xf8, dlogA, thrInt);
        collect_rescore<<<V / 256, 256, 0, stream>>>(dlogA, thrInt, lm_head, x_row, resKey);
    }
    finalize_kernel<<<1, 64, 0, stream>>>(resKey, out, K - 1);
}